// Round 1
// baseline (3570.448 us; speedup 1.0000x reference)
//
#include <hip/hip_runtime.h>

#define N_NODES 100000
#define N_EDGES 1600000
#define FEAT_D 300
#define HID_D 64

// ---------------- degree ----------------
__global__ void deg_kernel(const int* __restrict__ edges, float* __restrict__ deg) {
    int e = blockIdx.x * blockDim.x + threadIdx.x;
    if (e < N_EDGES) atomicAdd(&deg[edges[2 * e + 1]], 1.0f);
}

__global__ void invdeg_kernel(float* __restrict__ deg) {
    int i = blockIdx.x * blockDim.x + threadIdx.x;
    if (i < N_NODES) {
        float d = deg[i];
        deg[i] = d > 0.f ? 1.f / d : 0.f;
    }
}

// ---------------- dense GEMM: x(N x K) @ w(K x 64) -> out(N x 64) ----------------
// block = 256 threads = 4 waves; wave r computes row (blockIdx*4 + r), lane = col.
// w staged in LDS in 128-row chunks (32 KB).
template <int K>
__global__ void gemm_kernel(const float* __restrict__ x, const float* __restrict__ w,
                            float* __restrict__ out) {
    __shared__ float lw[128 * 64];
    const int col = threadIdx.x & 63;
    const int r = threadIdx.x >> 6;
    const long row = (long)blockIdx.x * 4 + r;
    const float* xr = x + row * K;
    float acc = 0.f;
    for (int k0 = 0; k0 < K; k0 += 128) {
        const int kc = (K - k0 < 128) ? (K - k0) : 128;
        __syncthreads();
        for (int i = threadIdx.x; i < kc * 16; i += 256)  // kc*64/4 float4s
            ((float4*)lw)[i] = ((const float4*)(w + (long)k0 * 64))[i];
        __syncthreads();
#pragma unroll 8
        for (int k = 0; k < kc; ++k)
            acc = fmaf(xr[k0 + k], lw[k * 64 + col], acc);
    }
    out[row * 64 + col] = acc;
}

// ---------------- SpMM: out[row] += h[col] * invdeg[row], atomic baseline ----------------
// 16 threads per edge, 4 floats (one float4 gather) each.
__global__ void spmm_kernel(const int* __restrict__ edges, const float* __restrict__ invdeg,
                            const float* __restrict__ h, float* __restrict__ out) {
    long tid = (long)blockIdx.x * blockDim.x + threadIdx.x;
    int e = (int)(tid >> 4);
    if (e >= N_EDGES) return;
    int f = ((int)tid & 15) * 4;
    int col = edges[2 * e];
    int row = edges[2 * e + 1];
    float wgt = invdeg[row];
    float4 v = *(const float4*)(h + (long)col * 64 + f);
    float* o = out + (long)row * 64 + f;
    atomicAdd(o + 0, v.x * wgt);
    atomicAdd(o + 1, v.y * wgt);
    atomicAdd(o + 2, v.z * wgt);
    atomicAdd(o + 3, v.w * wgt);
}

// ---------------- bias + leaky_relu(0.2) + row L2-normalize (in place) ----------------
// one wave (64 lanes) per row of 64 features.
__global__ void bias_act_norm_kernel(float* __restrict__ x, const float* __restrict__ b) {
    int row = blockIdx.x * 4 + (threadIdx.x >> 6);
    int lane = threadIdx.x & 63;
    float v = x[(long)row * 64 + lane] + b[lane];
    v = v >= 0.f ? v : 0.2f * v;
    float s = v * v;
#pragma unroll
    for (int off = 32; off > 0; off >>= 1) s += __shfl_xor(s, off);
    x[(long)row * 64 + lane] = v / fmaxf(sqrtf(s), 1e-12f);
}

// ---------------- gather label rows ----------------
__global__ void gather_kernel(const float* __restrict__ x, const int* __restrict__ idx,
                              float* __restrict__ out) {
    int i = blockIdx.x * blockDim.x + threadIdx.x;
    if (i < 1000 * 64) {
        int r = i >> 6;
        out[i] = x[(long)idx[r] * 64 + (i & 63)];
    }
}

extern "C" void kernel_launch(void* const* d_in, const int* in_sizes, int n_in,
                              void* d_out, int out_size, void* d_ws, size_t ws_size,
                              hipStream_t stream) {
    const int* edges = (const int*)d_in[0];
    const float* feat = (const float*)d_in[1];
    const int* label_idx = (const int*)d_in[2];
    const float* w1 = (const float*)d_in[3];
    const float* b1 = (const float*)d_in[4];
    const float* w2 = (const float*)d_in[5];
    const float* b2 = (const float*)d_in[6];
    float* out = (float*)d_out;

    float* deg = (float*)d_ws;                 // N floats (becomes inv_deg in place)
    float* bufA = deg + 100096;                // N*64
    float* bufB = bufA + (long)N_NODES * 64;   // N*64
    float* bufC = bufB + (long)N_NODES * 64;   // N*64

    hipMemsetAsync(deg, 0, N_NODES * sizeof(float), stream);
    deg_kernel<<<(N_EDGES + 255) / 256, 256, 0, stream>>>(edges, deg);
    invdeg_kernel<<<(N_NODES + 255) / 256, 256, 0, stream>>>(deg);

    // layer 1
    gemm_kernel<FEAT_D><<<N_NODES / 4, 256, 0, stream>>>(feat, w1, bufA);
    hipMemsetAsync(bufB, 0, (size_t)N_NODES * 64 * sizeof(float), stream);
    spmm_kernel<<<(int)(((long)N_EDGES * 16) / 256), 256, 0, stream>>>(edges, deg, bufA, bufB);
    bias_act_norm_kernel<<<N_NODES / 4, 256, 0, stream>>>(bufB, b1);

    // layer 2
    gemm_kernel<HID_D><<<N_NODES / 4, 256, 0, stream>>>(bufB, w2, bufA);
    hipMemsetAsync(bufC, 0, (size_t)N_NODES * 64 * sizeof(float), stream);
    spmm_kernel<<<(int)(((long)N_EDGES * 16) / 256), 256, 0, stream>>>(edges, deg, bufA, bufC);
    bias_act_norm_kernel<<<N_NODES / 4, 256, 0, stream>>>(bufC, b2);

    gather_kernel<<<(1000 * 64 + 255) / 256, 256, 0, stream>>>(bufC, label_idx, out);
}

// Round 2
// 1124.769 us; speedup vs baseline: 3.1744x; 3.1744x over previous
//
#include <hip/hip_runtime.h>

#define N_NODES 100000
#define N_EDGES 1600000
#define FEAT_D 300
#define HID_D 64
#define SCAN_NB 98  // ceil(100000/1024)

// ---------------- degree histogram (int) ----------------
__global__ void hist_kernel(const int* __restrict__ edges, int* __restrict__ cnt) {
    int e = blockIdx.x * blockDim.x + threadIdx.x;
    if (e < N_EDGES) atomicAdd(&cnt[edges[2 * e + 1]], 1);
}

__global__ void invdeg_kernel(const int* __restrict__ cnt, float* __restrict__ invdeg) {
    int i = blockIdx.x * blockDim.x + threadIdx.x;
    if (i < N_NODES) {
        int d = cnt[i];
        invdeg[i] = d > 0 ? 1.f / (float)d : 0.f;
    }
}

// ---------------- exclusive scan (3-kernel), 1024 elems/block ----------------
__global__ void scan1_kernel(const int* __restrict__ cnt, int* __restrict__ rp,
                             int* __restrict__ bsum) {
    __shared__ int sh[256];
    int base = blockIdx.x * 1024 + threadIdx.x * 4;
    int v[4];
    int s = 0;
#pragma unroll
    for (int j = 0; j < 4; ++j) {
        int idx = base + j;
        v[j] = (idx < N_NODES) ? cnt[idx] : 0;
        s += v[j];
    }
    sh[threadIdx.x] = s;
    __syncthreads();
    for (int off = 1; off < 256; off <<= 1) {
        int t = (threadIdx.x >= off) ? sh[threadIdx.x - off] : 0;
        __syncthreads();
        sh[threadIdx.x] += t;
        __syncthreads();
    }
    int excl = sh[threadIdx.x] - s;
    if (threadIdx.x == 255) bsum[blockIdx.x] = sh[255];
#pragma unroll
    for (int j = 0; j < 4; ++j) {
        int idx = base + j;
        if (idx < N_NODES) rp[idx] = excl;
        excl += v[j];
    }
}

__global__ void scan2_kernel(int* __restrict__ bsum, int* __restrict__ rp) {
    if (threadIdx.x == 0 && blockIdx.x == 0) {
        int acc = 0;
        for (int i = 0; i < SCAN_NB; ++i) {
            int t = bsum[i];
            bsum[i] = acc;
            acc += t;
        }
        rp[N_NODES] = acc;  // == N_EDGES
    }
}

__global__ void scan3_kernel(int* __restrict__ rp, const int* __restrict__ bsum) {
    int base = blockIdx.x * 1024 + threadIdx.x * 4;
    int add = bsum[blockIdx.x];
#pragma unroll
    for (int j = 0; j < 4; ++j) {
        int idx = base + j;
        if (idx < N_NODES) rp[idx] += add;
    }
}

// ---------------- scatter edges into CSR ----------------
__global__ void scatter_kernel(const int* __restrict__ edges, const int* __restrict__ rp,
                               int* __restrict__ cursor, int* __restrict__ csr_col) {
    int e = blockIdx.x * blockDim.x + threadIdx.x;
    if (e < N_EDGES) {
        int row = edges[2 * e + 1];
        int p = rp[row] + atomicAdd(&cursor[row], 1);
        csr_col[p] = edges[2 * e];
    }
}

// ---------------- dense GEMM: x(N x K) @ w(K x 64) -> out(N x 64) ----------------
template <int K>
__global__ void gemm_kernel(const float* __restrict__ x, const float* __restrict__ w,
                            float* __restrict__ out) {
    __shared__ float lw[128 * 64];
    const int col = threadIdx.x & 63;
    const int r = threadIdx.x >> 6;
    const long row = (long)blockIdx.x * 4 + r;
    const float* xr = x + row * K;
    float acc = 0.f;
    for (int k0 = 0; k0 < K; k0 += 128) {
        const int kc = (K - k0 < 128) ? (K - k0) : 128;
        __syncthreads();
        for (int i = threadIdx.x; i < kc * 16; i += 256)
            ((float4*)lw)[i] = ((const float4*)(w + (long)k0 * 64))[i];
        __syncthreads();
#pragma unroll 8
        for (int k = 0; k < kc; ++k)
            acc = fmaf(xr[k0 + k], lw[k * 64 + col], acc);
    }
    out[row * 64 + col] = acc;
}

// ---------------- fused CSR SpMM + bias + leaky_relu + l2norm ----------------
// one wave per row; lane = feature column.
__global__ void spmm_fused_kernel(const int* __restrict__ rp, const int* __restrict__ csr_col,
                                  const float* __restrict__ invdeg, const float* __restrict__ h,
                                  const float* __restrict__ b, float* __restrict__ out) {
    int row = blockIdx.x * 4 + (threadIdx.x >> 6);
    int lane = threadIdx.x & 63;
    int s = rp[row], e = rp[row + 1];
    float acc0 = 0.f, acc1 = 0.f;
    int i = s;
    for (; i + 2 <= e; i += 2) {
        int c0 = csr_col[i];
        int c1 = csr_col[i + 1];
        acc0 += h[(long)c0 * 64 + lane];
        acc1 += h[(long)c1 * 64 + lane];
    }
    if (i < e) acc0 += h[(long)csr_col[i] * 64 + lane];
    float v = (acc0 + acc1) * invdeg[row] + b[lane];
    v = v >= 0.f ? v : 0.2f * v;
    float ss = v * v;
#pragma unroll
    for (int off = 32; off > 0; off >>= 1) ss += __shfl_xor(ss, off);
    out[(long)row * 64 + lane] = v / fmaxf(sqrtf(ss), 1e-12f);
}

// ---------------- gather label rows ----------------
__global__ void gather_kernel(const float* __restrict__ x, const int* __restrict__ idx,
                              float* __restrict__ out) {
    int i = blockIdx.x * blockDim.x + threadIdx.x;
    if (i < 1000 * 64) {
        int r = i >> 6;
        out[i] = x[(long)idx[r] * 64 + (i & 63)];
    }
}

extern "C" void kernel_launch(void* const* d_in, const int* in_sizes, int n_in,
                              void* d_out, int out_size, void* d_ws, size_t ws_size,
                              hipStream_t stream) {
    const int* edges = (const int*)d_in[0];
    const float* feat = (const float*)d_in[1];
    const int* label_idx = (const int*)d_in[2];
    const float* w1 = (const float*)d_in[3];
    const float* b1 = (const float*)d_in[4];
    const float* w2 = (const float*)d_in[5];
    const float* b2 = (const float*)d_in[6];
    float* out = (float*)d_out;

    // workspace layout (all 4-byte elems, 16B-aligned chunks)
    int* cnt = (int*)d_ws;                    // 100352
    int* cursor = cnt + 100352;               // 100352
    int* rp = cursor + 100352;                // 100416 (needs N+1)
    int* bsum = rp + 100416;                  // 128
    float* invdeg = (float*)(bsum + 128);     // 100352
    int* csr_col = (int*)(invdeg + 100352);   // 1600000
    float* bufA = (float*)(csr_col + 1600000);    // N*64
    float* bufB = bufA + (long)N_NODES * 64;      // N*64

    // ---- CSR build ----
    hipMemsetAsync(cnt, 0, 2 * 100352 * sizeof(int), stream);  // cnt + cursor
    hist_kernel<<<(N_EDGES + 255) / 256, 256, 0, stream>>>(edges, cnt);
    invdeg_kernel<<<(N_NODES + 255) / 256, 256, 0, stream>>>(cnt, invdeg);
    scan1_kernel<<<SCAN_NB, 256, 0, stream>>>(cnt, rp, bsum);
    scan2_kernel<<<1, 64, 0, stream>>>(bsum, rp);
    scan3_kernel<<<SCAN_NB, 256, 0, stream>>>(rp, bsum);
    scatter_kernel<<<(N_EDGES + 255) / 256, 256, 0, stream>>>(edges, rp, cursor, csr_col);

    // ---- layer 1 ----
    gemm_kernel<FEAT_D><<<N_NODES / 4, 256, 0, stream>>>(feat, w1, bufA);
    spmm_fused_kernel<<<N_NODES / 4, 256, 0, stream>>>(rp, csr_col, invdeg, bufA, b1, bufB);

    // ---- layer 2 ----
    gemm_kernel<HID_D><<<N_NODES / 4, 256, 0, stream>>>(bufB, w2, bufA);
    spmm_fused_kernel<<<N_NODES / 4, 256, 0, stream>>>(rp, csr_col, invdeg, bufA, b2, bufB);

    gather_kernel<<<(1000 * 64 + 255) / 256, 256, 0, stream>>>(bufB, label_idx, out);
}

// Round 4
// 636.937 us; speedup vs baseline: 5.6057x; 1.7659x over previous
//
#include <hip/hip_runtime.h>

#define N_NODES 100000
#define N_EDGES 1600000
#define FEAT_D 300
#define HID_D 64
#define SCAN_NB 98  // ceil(100000/1024)

// ---------------- degree histogram (int) ----------------
__global__ void hist_kernel(const int* __restrict__ edges, int* __restrict__ cnt) {
    int e = blockIdx.x * blockDim.x + threadIdx.x;
    if (e < N_EDGES) atomicAdd(&cnt[edges[2 * e + 1]], 1);
}

__global__ void invdeg_kernel(const int* __restrict__ cnt, float* __restrict__ invdeg) {
    int i = blockIdx.x * blockDim.x + threadIdx.x;
    if (i < N_NODES) {
        int d = cnt[i];
        invdeg[i] = d > 0 ? 1.f / (float)d : 0.f;
    }
}

// ---------------- exclusive scan (3-kernel), 1024 elems/block ----------------
__global__ void scan1_kernel(const int* __restrict__ cnt, int* __restrict__ rp,
                             int* __restrict__ bsum) {
    __shared__ int sh[256];
    int base = blockIdx.x * 1024 + threadIdx.x * 4;
    int v[4];
    int s = 0;
#pragma unroll
    for (int j = 0; j < 4; ++j) {
        int idx = base + j;
        v[j] = (idx < N_NODES) ? cnt[idx] : 0;
        s += v[j];
    }
    sh[threadIdx.x] = s;
    __syncthreads();
    for (int off = 1; off < 256; off <<= 1) {
        int t = (threadIdx.x >= off) ? sh[threadIdx.x - off] : 0;
        __syncthreads();
        sh[threadIdx.x] += t;
        __syncthreads();
    }
    int excl = sh[threadIdx.x] - s;
    if (threadIdx.x == 255) bsum[blockIdx.x] = sh[255];
#pragma unroll
    for (int j = 0; j < 4; ++j) {
        int idx = base + j;
        if (idx < N_NODES) rp[idx] = excl;
        excl += v[j];
    }
}

__global__ void scan2_kernel(int* __restrict__ bsum, int* __restrict__ rp) {
    if (threadIdx.x == 0 && blockIdx.x == 0) {
        int acc = 0;
        for (int i = 0; i < SCAN_NB; ++i) {
            int t = bsum[i];
            bsum[i] = acc;
            acc += t;
        }
        rp[N_NODES] = acc;  // == N_EDGES
    }
}

__global__ void scan3_kernel(int* __restrict__ rp, const int* __restrict__ bsum) {
    int base = blockIdx.x * 1024 + threadIdx.x * 4;
    int add = bsum[blockIdx.x];
#pragma unroll
    for (int j = 0; j < 4; ++j) {
        int idx = base + j;
        if (idx < N_NODES) rp[idx] += add;
    }
}

// ---------------- scatter edges into CSR ----------------
__global__ void scatter_kernel(const int* __restrict__ edges, const int* __restrict__ rp,
                               int* __restrict__ cursor, int* __restrict__ csr_col) {
    int e = blockIdx.x * blockDim.x + threadIdx.x;
    if (e < N_EDGES) {
        int row = edges[2 * e + 1];
        int p = rp[row] + atomicAdd(&cursor[row], 1);
        csr_col[p] = edges[2 * e];
    }
}

// ---------------- register-tiled GEMM: x(N x K) @ w(K x 64) -> out(N x 64) ----------------
// block = 256 threads -> 128 rows x 64 cols tile; thread computes 4 rows x 8 cols.
// x chunk transposed in LDS (stride 132: 16B-aligned b128 reads, conflict-free),
// w chunk row-major (stride 64: 2-way conflict = free).
template <int K, int KC>
__global__ __launch_bounds__(256) void gemm_kernel(const float* __restrict__ x,
                                                   const float* __restrict__ w,
                                                   float* __restrict__ out) {
    constexpr int XSTR = 132;
    __shared__ __align__(16) float xT[KC * XSTR];
    __shared__ __align__(16) float wS[KC * 64];

    const int tid = threadIdx.x;
    const int c8 = (tid & 7) * 8;   // col base (0..56)
    const int r4 = (tid >> 3) * 4;  // row base within tile (0..124)
    const long r0 = (long)blockIdx.x * 128;

    float acc[4][8];
#pragma unroll
    for (int i = 0; i < 4; ++i)
#pragma unroll
        for (int j = 0; j < 8; ++j) acc[i][j] = 0.f;

    for (int k0 = 0; k0 < K; k0 += KC) {
        // ---- stage x chunk (transposed) ----
        constexpr int F4R = KC / 4;  // float4s per row
        for (int i = tid; i < 128 * F4R; i += 256) {
            int r = i / F4R, m = i % F4R;
            long gr = r0 + r;
            float4 v = make_float4(0.f, 0.f, 0.f, 0.f);
            if (gr < N_NODES) v = *(const float4*)(x + gr * K + k0 + 4 * m);
            xT[(4 * m + 0) * XSTR + r] = v.x;
            xT[(4 * m + 1) * XSTR + r] = v.y;
            xT[(4 * m + 2) * XSTR + r] = v.z;
            xT[(4 * m + 3) * XSTR + r] = v.w;
        }
        // ---- stage w chunk ----
        for (int i = tid; i < KC * 16; i += 256)
            ((float4*)wS)[i] = ((const float4*)(w + (long)k0 * 64))[i];
        __syncthreads();

#pragma unroll 4
        for (int k = 0; k < KC; ++k) {
            float4 xv = *(const float4*)&xT[k * XSTR + r4];
            float4 wa = *(const float4*)&wS[k * 64 + c8];
            float4 wb = *(const float4*)&wS[k * 64 + c8 + 4];
            const float* xp = &xv.x;
            const float* wap = &wa.x;
            const float* wbp = &wb.x;
#pragma unroll
            for (int i = 0; i < 4; ++i) {
                float xi = xp[i];
#pragma unroll
                for (int j = 0; j < 4; ++j) {
                    acc[i][j] = fmaf(xi, wap[j], acc[i][j]);
                    acc[i][j + 4] = fmaf(xi, wbp[j], acc[i][j + 4]);
                }
            }
        }
        __syncthreads();
    }

#pragma unroll
    for (int i = 0; i < 4; ++i) {
        long gr = r0 + r4 + i;
        if (gr < N_NODES) {
            *(float4*)(out + gr * 64 + c8) =
                make_float4(acc[i][0], acc[i][1], acc[i][2], acc[i][3]);
            *(float4*)(out + gr * 64 + c8 + 4) =
                make_float4(acc[i][4], acc[i][5], acc[i][6], acc[i][7]);
        }
    }
}

// ---------------- fused CSR SpMM + bias + leaky_relu + l2norm ----------------
// one wave per row; lane = feature column.
__global__ void spmm_fused_kernel(const int* __restrict__ rp, const int* __restrict__ csr_col,
                                  const float* __restrict__ invdeg, const float* __restrict__ h,
                                  const float* __restrict__ b, float* __restrict__ out) {
    int row = blockIdx.x * 4 + (threadIdx.x >> 6);
    int lane = threadIdx.x & 63;
    int s = rp[row], e = rp[row + 1];
    float acc0 = 0.f, acc1 = 0.f;
    int i = s;
    for (; i + 2 <= e; i += 2) {
        int c0 = csr_col[i];
        int c1 = csr_col[i + 1];
        acc0 += h[(long)c0 * 64 + lane];
        acc1 += h[(long)c1 * 64 + lane];
    }
    if (i < e) acc0 += h[(long)csr_col[i] * 64 + lane];
    float v = (acc0 + acc1) * invdeg[row] + b[lane];
    v = v >= 0.f ? v : 0.2f * v;
    float ss = v * v;
#pragma unroll
    for (int off = 32; off > 0; off >>= 1) ss += __shfl_xor(ss, off);
    out[(long)row * 64 + lane] = v / fmaxf(sqrtf(ss), 1e-12f);
}

// ---------------- gather label rows ----------------
__global__ void gather_kernel(const float* __restrict__ x, const int* __restrict__ idx,
                              float* __restrict__ out) {
    int i = blockIdx.x * blockDim.x + threadIdx.x;
    if (i < 1000 * 64) {
        int r = i >> 6;
        out[i] = x[(long)idx[r] * 64 + (i & 63)];
    }
}

extern "C" void kernel_launch(void* const* d_in, const int* in_sizes, int n_in,
                              void* d_out, int out_size, void* d_ws, size_t ws_size,
                              hipStream_t stream) {
    const int* edges = (const int*)d_in[0];
    const float* feat = (const float*)d_in[1];
    const int* label_idx = (const int*)d_in[2];
    const float* w1 = (const float*)d_in[3];
    const float* b1 = (const float*)d_in[4];
    const float* w2 = (const float*)d_in[5];
    const float* b2 = (const float*)d_in[6];
    float* out = (float*)d_out;

    // workspace layout (all 4-byte elems, 16B-aligned chunks)
    int* cnt = (int*)d_ws;                    // 100352
    int* cursor = cnt + 100352;               // 100352
    int* rp = cursor + 100352;                // 100416 (needs N+1)
    int* bsum = rp + 100416;                  // 128
    float* invdeg = (float*)(bsum + 128);     // 100352
    int* csr_col = (int*)(invdeg + 100352);   // 1600000
    float* bufA = (float*)(csr_col + 1600000);    // N*64
    float* bufB = bufA + (long)N_NODES * 64;      // N*64

    // ---- CSR build ----
    hipMemsetAsync(cnt, 0, 2 * 100352 * sizeof(int), stream);  // cnt + cursor
    hist_kernel<<<(N_EDGES + 255) / 256, 256, 0, stream>>>(edges, cnt);
    invdeg_kernel<<<(N_NODES + 255) / 256, 256, 0, stream>>>(cnt, invdeg);
    scan1_kernel<<<SCAN_NB, 256, 0, stream>>>(cnt, rp, bsum);
    scan2_kernel<<<1, 64, 0, stream>>>(bsum, rp);
    scan3_kernel<<<SCAN_NB, 256, 0, stream>>>(rp, bsum);
    scatter_kernel<<<(N_EDGES + 255) / 256, 256, 0, stream>>>(edges, rp, cursor, csr_col);

    const int gemm_blocks = (N_NODES + 127) / 128;  // 782

    // ---- layer 1 ----
    gemm_kernel<FEAT_D, 60><<<gemm_blocks, 256, 0, stream>>>(feat, w1, bufA);
    spmm_fused_kernel<<<N_NODES / 4, 256, 0, stream>>>(rp, csr_col, invdeg, bufA, b1, bufB);

    // ---- layer 2 ----
    gemm_kernel<HID_D, 64><<<gemm_blocks, 256, 0, stream>>>(bufB, w2, bufA);
    spmm_fused_kernel<<<N_NODES / 4, 256, 0, stream>>>(rp, csr_col, invdeg, bufA, b2, bufB);

    gather_kernel<<<(1000 * 64 + 255) / 256, 256, 0, stream>>>(bufB, label_idx, out);
}

// Round 7
// 572.007 us; speedup vs baseline: 6.2420x; 1.1135x over previous
//
#include <hip/hip_runtime.h>

#define N_NODES 100000
#define N_EDGES 1600000
#define FEAT_D 300
#define HID_D 64
#define SCAN_NB 98  // ceil(100000/1024)

// ---------------- degree histogram (int) ----------------
__global__ void hist_kernel(const int* __restrict__ edges, int* __restrict__ cnt) {
    int e = blockIdx.x * blockDim.x + threadIdx.x;
    if (e < N_EDGES) atomicAdd(&cnt[edges[2 * e + 1]], 1);
}

__global__ void invdeg_kernel(const int* __restrict__ cnt, float* __restrict__ invdeg) {
    int i = blockIdx.x * blockDim.x + threadIdx.x;
    if (i < N_NODES) {
        int d = cnt[i];
        invdeg[i] = d > 0 ? 1.f / (float)d : 0.f;
    }
}

// ---------------- exclusive scan (3-kernel), 1024 elems/block ----------------
__global__ void scan1_kernel(const int* __restrict__ cnt, int* __restrict__ rp,
                             int* __restrict__ bsum) {
    __shared__ int sh[256];
    int base = blockIdx.x * 1024 + threadIdx.x * 4;
    int v[4];
    int s = 0;
#pragma unroll
    for (int j = 0; j < 4; ++j) {
        int idx = base + j;
        v[j] = (idx < N_NODES) ? cnt[idx] : 0;
        s += v[j];
    }
    sh[threadIdx.x] = s;
    __syncthreads();
    for (int off = 1; off < 256; off <<= 1) {
        int t = (threadIdx.x >= off) ? sh[threadIdx.x - off] : 0;
        __syncthreads();
        sh[threadIdx.x] += t;
        __syncthreads();
    }
    int excl = sh[threadIdx.x] - s;
    if (threadIdx.x == 255) bsum[blockIdx.x] = sh[255];
#pragma unroll
    for (int j = 0; j < 4; ++j) {
        int idx = base + j;
        if (idx < N_NODES) rp[idx] = excl;
        excl += v[j];
    }
}

__global__ void scan2_kernel(int* __restrict__ bsum, int* __restrict__ rp) {
    if (threadIdx.x == 0 && blockIdx.x == 0) {
        int acc = 0;
        for (int i = 0; i < SCAN_NB; ++i) {
            int t = bsum[i];
            bsum[i] = acc;
            acc += t;
        }
        rp[N_NODES] = acc;  // == N_EDGES
    }
}

__global__ void scan3_kernel(int* __restrict__ rp, const int* __restrict__ bsum) {
    int base = blockIdx.x * 1024 + threadIdx.x * 4;
    int add = bsum[blockIdx.x];
#pragma unroll
    for (int j = 0; j < 4; ++j) {
        int idx = base + j;
        if (idx < N_NODES) rp[idx] += add;
    }
}

// ---------------- scatter edges into CSR ----------------
__global__ void scatter_kernel(const int* __restrict__ edges, const int* __restrict__ rp,
                               int* __restrict__ cursor, int* __restrict__ csr_col) {
    int e = blockIdx.x * blockDim.x + threadIdx.x;
    if (e < N_EDGES) {
        int row = edges[2 * e + 1];
        int p = rp[row] + atomicAdd(&cursor[row], 1);
        csr_col[p] = edges[2 * e];
    }
}

// ---------------- register-tiled GEMM: x(N x K) @ w(K x 64) -> out(N x 64) ----------------
// block = 256 threads -> 128 rows x 64 cols; thread (g = tid>>3, c8 = (tid&7)*8) computes
// rows {g, g+32, g+64, g+96} x cols c8..c8+7.
// xS row-major [128][68]: 68 floats = 17 x 16B units (odd) -> 8 row-groups of a wave hit
// 8 distinct bank-quads on ds_read_b128; staging writes are aligned b128 (2-way = free).
// Register prefetch pipeline: issue chunk c+1 global loads before computing chunk c.
template <int K, int KC>
__global__ __launch_bounds__(256) void gemm_kernel(const float* __restrict__ x,
                                                   const float* __restrict__ w,
                                                   float* __restrict__ out) {
    constexpr int XP = 68;
    constexpr int F4R = KC / 4;                    // float4s per x row chunk
    constexpr int NCH = K / KC;                    // chunks
    constexpr int NX = (128 * F4R + 255) / 256;    // x float4 loads per thread
    constexpr int NW = (KC * 16 + 255) / 256;      // w float4 loads per thread
    __shared__ __align__(16) float xS[128 * XP];
    __shared__ __align__(16) float wS[KC * 64];

    const int tid = threadIdx.x;
    const int g = tid >> 3;         // 0..31 row-group
    const int c8 = (tid & 7) * 8;   // col base
    const long r0 = (long)blockIdx.x * 128;

    float acc[4][8];
#pragma unroll
    for (int i = 0; i < 4; ++i)
#pragma unroll
        for (int j = 0; j < 8; ++j) acc[i][j] = 0.f;

    float4 pfx[NX];
    float4 pfw[NW];

    auto issue = [&](int k0) {
#pragma unroll
        for (int l = 0; l < NX; ++l) {
            int i = tid + l * 256;
            pfx[l] = make_float4(0.f, 0.f, 0.f, 0.f);
            if (i < 128 * F4R) {
                int r = i / F4R, m = i % F4R;
                long gr = r0 + r;
                if (gr < N_NODES) pfx[l] = *(const float4*)(x + gr * K + k0 + 4 * m);
            }
        }
#pragma unroll
        for (int l = 0; l < NW; ++l) {
            int i = tid + l * 256;
            if (i < KC * 16) pfw[l] = ((const float4*)(w + (long)k0 * 64))[i];
        }
    };
    auto commit = [&]() {
#pragma unroll
        for (int l = 0; l < NX; ++l) {
            int i = tid + l * 256;
            if (i < 128 * F4R) {
                int r = i / F4R, m = i % F4R;
                *(float4*)&xS[r * XP + 4 * m] = pfx[l];
            }
        }
#pragma unroll
        for (int l = 0; l < NW; ++l) {
            int i = tid + l * 256;
            if (i < KC * 16) ((float4*)wS)[i] = pfw[l];
        }
    };

    issue(0);
    commit();
    __syncthreads();

    for (int c = 0; c < NCH; ++c) {
        if (c + 1 < NCH) issue((c + 1) * KC);
#pragma unroll 3
        for (int k = 0; k < KC; k += 4) {
            float4 xv[4];
#pragma unroll
            for (int i = 0; i < 4; ++i)
                xv[i] = *(const float4*)&xS[(g + 32 * i) * XP + k];
#pragma unroll
            for (int kk = 0; kk < 4; ++kk) {
                float4 wa = *(const float4*)&wS[(k + kk) * 64 + c8];
                float4 wb = *(const float4*)&wS[(k + kk) * 64 + c8 + 4];
#pragma unroll
                for (int i = 0; i < 4; ++i) {
                    float xi = ((const float*)&xv[i])[kk];
                    acc[i][0] = fmaf(xi, wa.x, acc[i][0]);
                    acc[i][1] = fmaf(xi, wa.y, acc[i][1]);
                    acc[i][2] = fmaf(xi, wa.z, acc[i][2]);
                    acc[i][3] = fmaf(xi, wa.w, acc[i][3]);
                    acc[i][4] = fmaf(xi, wb.x, acc[i][4]);
                    acc[i][5] = fmaf(xi, wb.y, acc[i][5]);
                    acc[i][6] = fmaf(xi, wb.z, acc[i][6]);
                    acc[i][7] = fmaf(xi, wb.w, acc[i][7]);
                }
            }
        }
        __syncthreads();
        if (c + 1 < NCH) {
            commit();
            __syncthreads();
        }
    }

#pragma unroll
    for (int i = 0; i < 4; ++i) {
        long gr = r0 + g + 32 * i;
        if (gr < N_NODES) {
            *(float4*)(out + gr * 64 + c8) =
                make_float4(acc[i][0], acc[i][1], acc[i][2], acc[i][3]);
            *(float4*)(out + gr * 64 + c8 + 4) =
                make_float4(acc[i][4], acc[i][5], acc[i][6], acc[i][7]);
        }
    }
}

// ---------------- fused CSR SpMM + bias + leaky_relu + l2norm ----------------
// one wave per row; lane = (sub = lane>>4 -> edge slice, f4 = lane&15 -> feature quad).
// 4 edges in flight per gather instruction, 2-deep unroll -> 8 outstanding gathers/wave.
__global__ void spmm_fused_kernel(const int* __restrict__ rp, const int* __restrict__ csr_col,
                                  const float* __restrict__ invdeg, const float* __restrict__ h,
                                  const float* __restrict__ b, float* __restrict__ out) {
    int row = blockIdx.x * 4 + (threadIdx.x >> 6);
    int lane = threadIdx.x & 63;
    int sub = lane >> 4;
    int f4 = (lane & 15) * 4;
    int s = rp[row], e = rp[row + 1];

    float4 acc = make_float4(0.f, 0.f, 0.f, 0.f);
    int i = s + sub;
    for (; i + 4 < e; i += 8) {
        int c0 = csr_col[i];
        int c1 = csr_col[i + 4];
        float4 v0 = *(const float4*)(h + (long)c0 * 64 + f4);
        float4 v1 = *(const float4*)(h + (long)c1 * 64 + f4);
        acc.x += v0.x + v1.x;
        acc.y += v0.y + v1.y;
        acc.z += v0.z + v1.z;
        acc.w += v0.w + v1.w;
    }
    if (i < e) {
        int c0 = csr_col[i];
        float4 v0 = *(const float4*)(h + (long)c0 * 64 + f4);
        acc.x += v0.x;
        acc.y += v0.y;
        acc.z += v0.z;
        acc.w += v0.w;
    }

    // combine the 4 edge-slices (lanes differing in bits 4,5)
    acc.x += __shfl_xor(acc.x, 16);
    acc.y += __shfl_xor(acc.y, 16);
    acc.z += __shfl_xor(acc.z, 16);
    acc.w += __shfl_xor(acc.w, 16);
    acc.x += __shfl_xor(acc.x, 32);
    acc.y += __shfl_xor(acc.y, 32);
    acc.z += __shfl_xor(acc.z, 32);
    acc.w += __shfl_xor(acc.w, 32);

    float id = invdeg[row];
    float4 bb = *(const float4*)(b + f4);
    float4 v;
    v.x = acc.x * id + bb.x;
    v.y = acc.y * id + bb.y;
    v.z = acc.z * id + bb.z;
    v.w = acc.w * id + bb.w;
    v.x = v.x >= 0.f ? v.x : 0.2f * v.x;
    v.y = v.y >= 0.f ? v.y : 0.2f * v.y;
    v.z = v.z >= 0.f ? v.z : 0.2f * v.z;
    v.w = v.w >= 0.f ? v.w : 0.2f * v.w;

    float ss = v.x * v.x + v.y * v.y + v.z * v.z + v.w * v.w;
    ss += __shfl_xor(ss, 1);
    ss += __shfl_xor(ss, 2);
    ss += __shfl_xor(ss, 4);
    ss += __shfl_xor(ss, 8);
    float inv = 1.f / fmaxf(sqrtf(ss), 1e-12f);

    if (sub == 0) {
        v.x *= inv;
        v.y *= inv;
        v.z *= inv;
        v.w *= inv;
        *(float4*)(out + (long)row * 64 + f4) = v;
    }
}

// ---------------- gather label rows ----------------
__global__ void gather_kernel(const float* __restrict__ x, const int* __restrict__ idx,
                              float* __restrict__ out) {
    int i = blockIdx.x * blockDim.x + threadIdx.x;
    if (i < 1000 * 64) {
        int r = i >> 6;
        out[i] = x[(long)idx[r] * 64 + (i & 63)];
    }
}

extern "C" void kernel_launch(void* const* d_in, const int* in_sizes, int n_in,
                              void* d_out, int out_size, void* d_ws, size_t ws_size,
                              hipStream_t stream) {
    const int* edges = (const int*)d_in[0];
    const float* feat = (const float*)d_in[1];
    const int* label_idx = (const int*)d_in[2];
    const float* w1 = (const float*)d_in[3];
    const float* b1 = (const float*)d_in[4];
    const float* w2 = (const float*)d_in[5];
    const float* b2 = (const float*)d_in[6];
    float* out = (float*)d_out;

    // workspace layout (all 4-byte elems, 16B-aligned chunks)
    int* cnt = (int*)d_ws;                    // 100352
    int* cursor = cnt + 100352;               // 100352
    int* rp = cursor + 100352;                // 100416 (needs N+1)
    int* bsum = rp + 100416;                  // 128
    float* invdeg = (float*)(bsum + 128);     // 100352
    int* csr_col = (int*)(invdeg + 100352);   // 1600000
    float* bufA = (float*)(csr_col + 1600000);    // N*64
    float* bufB = bufA + (long)N_NODES * 64;      // N*64

    // ---- CSR build ----
    hipMemsetAsync(cnt, 0, 2 * 100352 * sizeof(int), stream);  // cnt + cursor
    hist_kernel<<<(N_EDGES + 255) / 256, 256, 0, stream>>>(edges, cnt);
    invdeg_kernel<<<(N_NODES + 255) / 256, 256, 0, stream>>>(cnt, invdeg);
    scan1_kernel<<<SCAN_NB, 256, 0, stream>>>(cnt, rp, bsum);
    scan2_kernel<<<1, 64, 0, stream>>>(bsum, rp);
    scan3_kernel<<<SCAN_NB, 256, 0, stream>>>(rp, bsum);
    scatter_kernel<<<(N_EDGES + 255) / 256, 256, 0, stream>>>(edges, rp, cursor, csr_col);

    const int gemm_blocks = (N_NODES + 127) / 128;  // 782

    // ---- layer 1 ----
    gemm_kernel<FEAT_D, 60><<<gemm_blocks, 256, 0, stream>>>(feat, w1, bufA);
    spmm_fused_kernel<<<N_NODES / 4, 256, 0, stream>>>(rp, csr_col, invdeg, bufA, b1, bufB);

    // ---- layer 2 ----
    gemm_kernel<HID_D, 64><<<gemm_blocks, 256, 0, stream>>>(bufB, w2, bufA);
    spmm_fused_kernel<<<N_NODES / 4, 256, 0, stream>>>(rp, csr_col, invdeg, bufA, b2, bufB);

    gather_kernel<<<(1000 * 64 + 255) / 256, 256, 0, stream>>>(bufB, label_idx, out);
}

// Round 9
// 521.428 us; speedup vs baseline: 6.8474x; 1.0970x over previous
//
#include <hip/hip_runtime.h>

#define N_NODES 100000
#define N_EDGES 1600000
#define FEAT_D 300
#define HID_D 64
#define SCAN_NB 98  // ceil(100000/1024)

typedef __attribute__((ext_vector_type(8))) short short8;
typedef __attribute__((ext_vector_type(4))) float f32x4;
typedef unsigned int u32;
typedef unsigned short u16;

// Dekker-style split: v = hi(bf16, truncated) + lo(bf16, RNE of exact residual).
__device__ inline void split2(float v, u16& h, u16& l) {
    u32 u = __float_as_uint(v);
    h = (u16)(u >> 16);                                   // truncate -> hi
    float lo = v - __uint_as_float(u & 0xffff0000u);      // exact residual
    u32 lu = __float_as_uint(lo);
    lu += 0x7fffu + ((lu >> 16) & 1u);                    // RNE to bf16
    l = (u16)(lu >> 16);
}

// ---------------- degree histogram (int) ----------------
__global__ void hist_kernel(const int* __restrict__ edges, int* __restrict__ cnt) {
    int e = blockIdx.x * blockDim.x + threadIdx.x;
    if (e < N_EDGES) atomicAdd(&cnt[edges[2 * e + 1]], 1);
}

__global__ void invdeg_kernel(const int* __restrict__ cnt, float* __restrict__ invdeg) {
    int i = blockIdx.x * blockDim.x + threadIdx.x;
    if (i < N_NODES) {
        int d = cnt[i];
        invdeg[i] = d > 0 ? 1.f / (float)d : 0.f;
    }
}

// ---------------- exclusive scan (3-kernel), 1024 elems/block ----------------
__global__ void scan1_kernel(const int* __restrict__ cnt, int* __restrict__ rp,
                             int* __restrict__ bsum) {
    __shared__ int sh[256];
    int base = blockIdx.x * 1024 + threadIdx.x * 4;
    int v[4];
    int s = 0;
#pragma unroll
    for (int j = 0; j < 4; ++j) {
        int idx = base + j;
        v[j] = (idx < N_NODES) ? cnt[idx] : 0;
        s += v[j];
    }
    sh[threadIdx.x] = s;
    __syncthreads();
    for (int off = 1; off < 256; off <<= 1) {
        int t = (threadIdx.x >= off) ? sh[threadIdx.x - off] : 0;
        __syncthreads();
        sh[threadIdx.x] += t;
        __syncthreads();
    }
    int excl = sh[threadIdx.x] - s;
    if (threadIdx.x == 255) bsum[blockIdx.x] = sh[255];
#pragma unroll
    for (int j = 0; j < 4; ++j) {
        int idx = base + j;
        if (idx < N_NODES) rp[idx] = excl;
        excl += v[j];
    }
}

__global__ void scan2_kernel(int* __restrict__ bsum, int* __restrict__ rp) {
    if (threadIdx.x == 0 && blockIdx.x == 0) {
        int acc = 0;
        for (int i = 0; i < SCAN_NB; ++i) {
            int t = bsum[i];
            bsum[i] = acc;
            acc += t;
        }
        rp[N_NODES] = acc;  // == N_EDGES
    }
}

__global__ void scan3_kernel(int* __restrict__ rp, const int* __restrict__ bsum) {
    int base = blockIdx.x * 1024 + threadIdx.x * 4;
    int add = bsum[blockIdx.x];
#pragma unroll
    for (int j = 0; j < 4; ++j) {
        int idx = base + j;
        if (idx < N_NODES) rp[idx] += add;
    }
}

// ---------------- scatter edges into CSR ----------------
__global__ void scatter_kernel(const int* __restrict__ edges, const int* __restrict__ rp,
                               int* __restrict__ cursor, int* __restrict__ csr_col) {
    int e = blockIdx.x * blockDim.x + threadIdx.x;
    if (e < N_EDGES) {
        int row = edges[2 * e + 1];
        int p = rp[row] + atomicAdd(&cursor[row], 1);
        csr_col[p] = edges[2 * e];
    }
}

// ---------------- one-time weight split+transpose: w(K x 64) -> wT{H,L}(64 x KW) bf16 ----------------
__global__ void wsplit_kernel(const float* __restrict__ w, u16* __restrict__ wtH,
                              u16* __restrict__ wtL, int K, int KW) {
    int id = blockIdx.x * blockDim.x + threadIdx.x;
    if (id >= 64 * KW) return;
    int c = id / KW, k = id % KW;
    float v = (k < K) ? w[(long)k * 64 + c] : 0.f;
    u16 h, l;
    split2(v, h, l);
    wtH[(long)c * KW + k] = h;
    wtL[(long)c * KW + k] = l;
}

// ---------------- MFMA split-bf16 GEMM: x(N x K) fp32 @ w(K x 64) -> out(N x 64) fp32 ----------------
// block = 256 = 4 waves; tile 128 rows x 64 cols; wave wm owns rows wm*32..wm*32+31.
// Per wave: 2 row-tiles x 4 col-tiles of 16x16, K-chunks of 32 via mfma_f32_16x16x32_bf16.
// Numerics: x = xh+xl, w = wh+wl (Dekker split); D = xh*wh + xh*wl + xl*wh (drop xl*wl ~2^-16).
// Fragment k-map kappa(g=lane>>4, j) = g*8+j used identically for A and B => any internal
// hardware K-order permutation cancels. C/D: col=lane&15, row=(lane>>4)*4+reg (m89-verified).
// A staged in LDS as bf16 hi/lo planes, row stride 40 (80 B, odd multiple of 16B).
// B fragments read directly from pre-split wT in global (L2-resident, 40-80 KB).
template <int K, int KW>
__global__ __launch_bounds__(256) void gemm_mfma(const float* __restrict__ x,
                                                 const u16* __restrict__ wtH,
                                                 const u16* __restrict__ wtL,
                                                 float* __restrict__ out) {
    constexpr int NCH = (K + 31) / 32;
    constexpr int RS = 40;  // LDS row stride (bf16 elems)
    __shared__ __align__(16) u16 aH[128 * RS];
    __shared__ __align__(16) u16 aL[128 * RS];

    const int tid = threadIdx.x;
    const int lane = tid & 63;
    const int wm = tid >> 6;
    const int l15 = lane & 15;
    const int lg = lane >> 4;
    const long r0 = (long)blockIdx.x * 128;

    f32x4 acc[2][4];
#pragma unroll
    for (int i = 0; i < 2; ++i)
#pragma unroll
        for (int j = 0; j < 4; ++j)
#pragma unroll
            for (int e = 0; e < 4; ++e) acc[i][j][e] = 0.f;

    // staging: thread -> (rows sr+32l, float4 sm) of the 128x32 fp32 chunk
    const int sr = tid >> 3;
    const int sm = tid & 7;
    float4 pf[4];

    auto issueA = [&](int k0) {
#pragma unroll
        for (int l = 0; l < 4; ++l) {
            long gr = r0 + sr + 32 * l;
            float4 v = make_float4(0.f, 0.f, 0.f, 0.f);
            bool kok = (K % 32 == 0) || (k0 + 4 * sm + 3 < K);
            if (gr < N_NODES && kok) v = *(const float4*)(x + gr * K + k0 + 4 * sm);
            pf[l] = v;
        }
    };
    auto commitA = [&]() {
#pragma unroll
        for (int l = 0; l < 4; ++l) {
            int r = sr + 32 * l;
            u16 h0, h1, h2, h3, q0, q1, q2, q3;
            split2(pf[l].x, h0, q0);
            split2(pf[l].y, h1, q1);
            split2(pf[l].z, h2, q2);
            split2(pf[l].w, h3, q3);
            uint2 ph = make_uint2((u32)h0 | ((u32)h1 << 16), (u32)h2 | ((u32)h3 << 16));
            uint2 pl = make_uint2((u32)q0 | ((u32)q1 << 16), (u32)q2 | ((u32)q3 << 16));
            *(uint2*)&aH[r * RS + 4 * sm] = ph;
            *(uint2*)&aL[r * RS + 4 * sm] = pl;
        }
    };

    issueA(0);
    commitA();
    __syncthreads();

    for (int c = 0; c < NCH; ++c) {
        const int k0 = c * 32;
        if (c + 1 < NCH) issueA(k0 + 32);  // next chunk's global loads in flight over compute

        short8 bh[4], bl[4];
#pragma unroll
        for (int ct = 0; ct < 4; ++ct) {
            long off = (long)(ct * 16 + l15) * KW + k0 + lg * 8;
            bh[ct] = *(const short8*)(wtH + off);
            bl[ct] = *(const short8*)(wtL + off);
        }
        short8 ah[2], al[2];
#pragma unroll
        for (int rt = 0; rt < 2; ++rt) {
            int row = wm * 32 + rt * 16 + l15;
            ah[rt] = *(const short8*)&aH[row * RS + lg * 8];
            al[rt] = *(const short8*)&aL[row * RS + lg * 8];
        }
#pragma unroll
        for (int rt = 0; rt < 2; ++rt)
#pragma unroll
            for (int ct = 0; ct < 4; ++ct) {
                acc[rt][ct] = __builtin_amdgcn_mfma_f32_16x16x32_bf16(ah[rt], bh[ct], acc[rt][ct], 0, 0, 0);
                acc[rt][ct] = __builtin_amdgcn_mfma_f32_16x16x32_bf16(ah[rt], bl[ct], acc[rt][ct], 0, 0, 0);
                acc[rt][ct] = __builtin_amdgcn_mfma_f32_16x16x32_bf16(al[rt], bh[ct], acc[rt][ct], 0, 0, 0);
            }
        __syncthreads();
        if (c + 1 < NCH) {
            commitA();
            __syncthreads();
        }
    }

#pragma unroll
    for (int rt = 0; rt < 2; ++rt) {
        int rbase = wm * 32 + rt * 16 + lg * 4;
#pragma unroll
        for (int reg = 0; reg < 4; ++reg) {
            long gr = r0 + rbase + reg;
            if (gr < N_NODES) {
#pragma unroll
                for (int ct = 0; ct < 4; ++ct)
                    out[gr * 64 + ct * 16 + l15] = acc[rt][ct][reg];
            }
        }
    }
}

// ---------------- fused CSR SpMM + bias + leaky_relu + l2norm ----------------
__global__ void spmm_fused_kernel(const int* __restrict__ rp, const int* __restrict__ csr_col,
                                  const float* __restrict__ invdeg, const float* __restrict__ h,
                                  const float* __restrict__ b, float* __restrict__ out) {
    int row = blockIdx.x * 4 + (threadIdx.x >> 6);
    int lane = threadIdx.x & 63;
    int sub = lane >> 4;
    int f4 = (lane & 15) * 4;
    int s = rp[row], e = rp[row + 1];

    float4 acc = make_float4(0.f, 0.f, 0.f, 0.f);
    int i = s + sub;
    for (; i + 4 < e; i += 8) {
        int c0 = csr_col[i];
        int c1 = csr_col[i + 4];
        float4 v0 = *(const float4*)(h + (long)c0 * 64 + f4);
        float4 v1 = *(const float4*)(h + (long)c1 * 64 + f4);
        acc.x += v0.x + v1.x;
        acc.y += v0.y + v1.y;
        acc.z += v0.z + v1.z;
        acc.w += v0.w + v1.w;
    }
    if (i < e) {
        int c0 = csr_col[i];
        float4 v0 = *(const float4*)(h + (long)c0 * 64 + f4);
        acc.x += v0.x;
        acc.y += v0.y;
        acc.z += v0.z;
        acc.w += v0.w;
    }

    acc.x += __shfl_xor(acc.x, 16);
    acc.y += __shfl_xor(acc.y, 16);
    acc.z += __shfl_xor(acc.z, 16);
    acc.w += __shfl_xor(acc.w, 16);
    acc.x += __shfl_xor(acc.x, 32);
    acc.y += __shfl_xor(acc.y, 32);
    acc.z += __shfl_xor(acc.z, 32);
    acc.w += __shfl_xor(acc.w, 32);

    float id = invdeg[row];
    float4 bb = *(const float4*)(b + f4);
    float4 v;
    v.x = acc.x * id + bb.x;
    v.y = acc.y * id + bb.y;
    v.z = acc.z * id + bb.z;
    v.w = acc.w * id + bb.w;
    v.x = v.x >= 0.f ? v.x : 0.2f * v.x;
    v.y = v.y >= 0.f ? v.y : 0.2f * v.y;
    v.z = v.z >= 0.f ? v.z : 0.2f * v.z;
    v.w = v.w >= 0.f ? v.w : 0.2f * v.w;

    float ss = v.x * v.x + v.y * v.y + v.z * v.z + v.w * v.w;
    ss += __shfl_xor(ss, 1);
    ss += __shfl_xor(ss, 2);
    ss += __shfl_xor(ss, 4);
    ss += __shfl_xor(ss, 8);
    float inv = 1.f / fmaxf(sqrtf(ss), 1e-12f);

    if (sub == 0) {
        v.x *= inv;
        v.y *= inv;
        v.z *= inv;
        v.w *= inv;
        *(float4*)(out + (long)row * 64 + f4) = v;
    }
}

// ---------------- gather label rows ----------------
__global__ void gather_kernel(const float* __restrict__ x, const int* __restrict__ idx,
                              float* __restrict__ out) {
    int i = blockIdx.x * blockDim.x + threadIdx.x;
    if (i < 1000 * 64) {
        int r = i >> 6;
        out[i] = x[(long)idx[r] * 64 + (i & 63)];
    }
}

extern "C" void kernel_launch(void* const* d_in, const int* in_sizes, int n_in,
                              void* d_out, int out_size, void* d_ws, size_t ws_size,
                              hipStream_t stream) {
    const int* edges = (const int*)d_in[0];
    const float* feat = (const float*)d_in[1];
    const int* label_idx = (const int*)d_in[2];
    const float* w1 = (const float*)d_in[3];
    const float* b1 = (const float*)d_in[4];
    const float* w2 = (const float*)d_in[5];
    const float* b2 = (const float*)d_in[6];
    float* out = (float*)d_out;

    // workspace layout (4-byte elems, 16B-aligned chunks)
    int* cnt = (int*)d_ws;                    // 100352
    int* cursor = cnt + 100352;               // 100352
    int* rp = cursor + 100352;                // 100416 (needs N+1)
    int* bsum = rp + 100416;                  // 128
    float* invdeg = (float*)(bsum + 128);     // 100352
    int* csr_col = (int*)(invdeg + 100352);   // 1600000
    float* bufA = (float*)(csr_col + 1600000);    // N*64
    float* bufB = bufA + (long)N_NODES * 64;      // N*64
    u16* wt1H = (u16*)(bufB + (long)N_NODES * 64);  // 64*320
    u16* wt1L = wt1H + 64 * 320;
    u16* wt2H = wt1L + 64 * 320;              // 64*64
    u16* wt2L = wt2H + 64 * 64;

    // ---- CSR build + weight split (independent) ----
    hipMemsetAsync(cnt, 0, 2 * 100352 * sizeof(int), stream);  // cnt + cursor
    wsplit_kernel<<<(64 * 320 + 255) / 256, 256, 0, stream>>>(w1, wt1H, wt1L, 300, 320);
    wsplit_kernel<<<(64 * 64 + 255) / 256, 256, 0, stream>>>(w2, wt2H, wt2L, 64, 64);
    hist_kernel<<<(N_EDGES + 255) / 256, 256, 0, stream>>>(edges, cnt);
    invdeg_kernel<<<(N_NODES + 255) / 256, 256, 0, stream>>>(cnt, invdeg);
    scan1_kernel<<<SCAN_NB, 256, 0, stream>>>(cnt, rp, bsum);
    scan2_kernel<<<1, 64, 0, stream>>>(bsum, rp);
    scan3_kernel<<<SCAN_NB, 256, 0, stream>>>(rp, bsum);
    scatter_kernel<<<(N_EDGES + 255) / 256, 256, 0, stream>>>(edges, rp, cursor, csr_col);

    const int gemm_blocks = (N_NODES + 127) / 128;  // 782

    // ---- layer 1 ----
    gemm_mfma<FEAT_D, 320><<<gemm_blocks, 256, 0, stream>>>(feat, wt1H, wt1L, bufA);
    spmm_fused_kernel<<<N_NODES / 4, 256, 0, stream>>>(rp, csr_col, invdeg, bufA, b1, bufB);

    // ---- layer 2 ----
    gemm_mfma<HID_D, 64><<<gemm_blocks, 256, 0, stream>>>(bufB, wt2H, wt2L, bufA);
    spmm_fused_kernel<<<N_NODES / 4, 256, 0, stream>>>(rp, csr_col, invdeg, bufA, b2, bufB);

    gather_kernel<<<(1000 * 64 + 255) / 256, 256, 0, stream>>>(bufB, label_idx, out);
}